// Round 1
// baseline (668.455 us; speedup 1.0000x reference)
//
#include <hip/hip_runtime.h>

// MHA: B=2048, N=144, H=4, d=32. qkv [B,144,384] fp32, mask [1,4,144,144] fp32,
// out [B,144,128] fp32. One block per (b,h). bf16 MFMA 16x16x32 (K=32=head_dim).
//
// v2: swapped-operand QK^T (S^T in regs -> q-row lane-local) + T12 in-register
// P redistribution (cvt_pk_bf16 + permlane32_swap + permlane16_swap).
// Deletes sP (21.5 KB LDS) and the P LDS round-trip; softmax needs only
// 2 shuffles per reduce; mask loads become float4. LDS 48.4->26.9 KB,
// launch_bounds(256,4): 4 blocks/CU instead of 3.

using short8 = __attribute__((ext_vector_type(8))) short;
using f32x4  = __attribute__((ext_vector_type(4))) float;
using uint2v = __attribute__((ext_vector_type(2))) unsigned int;

#define SEQ   144
#define NH    4
#define HD    32
#define C3    384   // 3*NH*HD
#define OC    128   // NH*HD

#define KSTR  56    // sK row stride (ushort): 112 B = 16B-aligned, conflict-free for b128
#define VSTR  168   // sVT row stride: 336 B = 16B-aligned, conflict-free

#define LOG2E 1.4426950408889634f
#define SCALE 0.17677669529663687f

__device__ __forceinline__ unsigned short f2bf(float f) {
  unsigned int u = __float_as_uint(f);
  u += 0x7fffu + ((u >> 16) & 1u);   // round-nearest-even to bf16
  return (unsigned short)(u >> 16);
}

__device__ __forceinline__ unsigned int cvt_pk_bf16(float lo, float hi) {
  unsigned int r;
  asm("v_cvt_pk_bf16_f32 %0, %1, %2" : "=v"(r) : "v"(lo), "v"(hi));
  return r;
}

__global__ __launch_bounds__(256, 4)
void attn_kernel(const float* __restrict__ qkv,
                 const float* __restrict__ mask,
                 float* __restrict__ out)
{
  __shared__ __align__(16) unsigned short sK [SEQ * KSTR];    // 16128 B
  __shared__ __align__(16) unsigned short sVT[HD  * VSTR];    // 10752 B

  const int tid = threadIdx.x;
  const int bid = blockIdx.x;
  const int b = bid >> 2;
  const int h = bid & 3;

  const float* qbase = qkv + (size_t)b * (SEQ * C3) + h * HD;
  const float* kbase = qbase + NH * HD;       // t=1 slice
  const float* vbase = qbase + 2 * NH * HD;   // t=2 slice

  // ---- stage K as bf16 [144][KSTR] ----
  {
    const int n0 = tid >> 4;           // 0..15
    const int d2 = (tid & 15) * 2;     // 0..30
    #pragma unroll
    for (int p = 0; p < 9; ++p) {
      int n = p * 16 + n0;
      float2 kv2 = *(const float2*)(kbase + (size_t)n * C3 + d2);
      unsigned int pk = (unsigned int)f2bf(kv2.x) | ((unsigned int)f2bf(kv2.y) << 16);
      *(unsigned int*)&sK[n * KSTR + d2] = pk;
    }
  }
  // ---- stage V transposed: sVT[d][n] = V[n][d], zero-pad cols 144..167 ----
  {
    const int d  = tid & 31;
    const int n0 = tid >> 5;           // 0..7
    #pragma unroll
    for (int p = 0; p < 18; ++p) {
      int n = p * 8 + n0;
      sVT[d * VSTR + n] = f2bf(vbase[(size_t)n * C3 + d]);
    }
    const int r  = tid >> 3;           // 0..31
    const int c0 = tid & 7;
    #pragma unroll
    for (int p = 0; p < 3; ++p)
      sVT[r * VSTR + 144 + c0 + p * 8] = 0;
  }
  __syncthreads();

  const int lane = tid & 63;
  const int wv   = tid >> 6;
  const int m    = lane & 15;
  const int quad = lane >> 4;

  const float qs = SCALE * LOG2E;      // fold softmax scale + log2(e) into Q
  const float* mbase = mask + (size_t)h * SEQ * SEQ;

  for (int s = wv; s < 9; s += 4) {
    const int qr = s * 16 + m;         // q-row this lane owns (S^T layout)

    // ---- Q fragment (B-operand: lane m holds Q[qr][quad*8 + j]) ----
    short8 qfrag;
    {
      const float* qrow = qbase + (size_t)qr * C3 + quad * 8;
      float4 q0 = *(const float4*)(qrow);
      float4 q1 = *(const float4*)(qrow + 4);
      qfrag[0] = (short)f2bf(q0.x * qs); qfrag[1] = (short)f2bf(q0.y * qs);
      qfrag[2] = (short)f2bf(q0.z * qs); qfrag[3] = (short)f2bf(q0.w * qs);
      qfrag[4] = (short)f2bf(q1.x * qs); qfrag[5] = (short)f2bf(q1.y * qs);
      qfrag[6] = (short)f2bf(q1.z * qs); qfrag[7] = (short)f2bf(q1.w * qs);
    }

    // ---- S^T = K (Q*scale)^T + mask (log2 domain).
    // mfma(A=K, B=Q): lane (m,quad) reg r = S[q=qr][kv = nt*16 + quad*4 + r].
    float p[9][4];
    const float* mrow = mbase + (size_t)qr * SEQ + quad * 4;
    #pragma unroll
    for (int nt = 0; nt < 9; ++nt) {
      f32x4 c = {0.f, 0.f, 0.f, 0.f};
      short8 kfrag = *(const short8*)&sK[(nt * 16 + m) * KSTR + quad * 8];
      c = __builtin_amdgcn_mfma_f32_16x16x32_bf16(kfrag, qfrag, c, 0, 0, 0);
      float4 mk = *(const float4*)(mrow + nt * 16);
      p[nt][0] = c[0] + mk.x * LOG2E;
      p[nt][1] = c[1] + mk.y * LOG2E;
      p[nt][2] = c[2] + mk.z * LOG2E;
      p[nt][3] = c[3] + mk.w * LOG2E;
    }

    // ---- softmax: full row is local to lanes {m, m+16, m+32, m+48} ----
    float t[9];
    #pragma unroll
    for (int nt = 0; nt < 9; ++nt)
      t[nt] = fmaxf(fmaxf(p[nt][0], p[nt][1]), fmaxf(p[nt][2], p[nt][3]));
    float mx = fmaxf(fmaxf(fmaxf(t[0], t[1]), fmaxf(t[2], t[3])),
                     fmaxf(fmaxf(t[4], t[5]), fmaxf(t[6], t[7])));
    mx = fmaxf(mx, t[8]);
    mx = fmaxf(mx, __shfl_xor(mx, 16));
    mx = fmaxf(mx, __shfl_xor(mx, 32));

    float s0 = 0.f, s1 = 0.f, s2 = 0.f, s3 = 0.f;
    #pragma unroll
    for (int nt = 0; nt < 9; ++nt) {
      p[nt][0] = __builtin_amdgcn_exp2f(p[nt][0] - mx); s0 += p[nt][0];
      p[nt][1] = __builtin_amdgcn_exp2f(p[nt][1] - mx); s1 += p[nt][1];
      p[nt][2] = __builtin_amdgcn_exp2f(p[nt][2] - mx); s2 += p[nt][2];
      p[nt][3] = __builtin_amdgcn_exp2f(p[nt][3] - mx); s3 += p[nt][3];
    }
    float sum = (s0 + s1) + (s2 + s3);
    sum += __shfl_xor(sum, 16);
    sum += __shfl_xor(sum, 32);
    const float il = 1.0f / sum;       // defer normalization to epilogue

    // ---- O = P V. P redistributed C-layout -> A-layout in registers:
    // per kt: pack pairs (E:even nt, O:odd nt), permlane32_swap puts even-nt
    // data in lanes 0-31 / odd-nt in 32-63 (E') and Q2Q3 data in O';
    // permlane16_swap(E',O') yields A-frag words (w0,w2) directly.
    f32x4 acc0 = {0.f, 0.f, 0.f, 0.f}, acc1 = {0.f, 0.f, 0.f, 0.f};
    #pragma unroll
    for (int kt = 0; kt < 5; ++kt) {
      unsigned int E0 = cvt_pk_bf16(p[2 * kt][0], p[2 * kt][1]);
      unsigned int E1 = cvt_pk_bf16(p[2 * kt][2], p[2 * kt][3]);
      unsigned int O0 = 0, O1 = 0;
      if (kt < 4) {   // kt=4 odd tile (kv 144..159) is the zero pad
        O0 = cvt_pk_bf16(p[2 * kt + 1][0], p[2 * kt + 1][1]);
        O1 = cvt_pk_bf16(p[2 * kt + 1][2], p[2 * kt + 1][3]);
      }
      uint2v sA  = __builtin_amdgcn_permlane32_swap(E0, O0, false, false);
      uint2v sB  = __builtin_amdgcn_permlane32_swap(E1, O1, false, false);
      uint2v w02 = __builtin_amdgcn_permlane16_swap(sA[0], sA[1], false, false);
      uint2v w13 = __builtin_amdgcn_permlane16_swap(sB[0], sB[1], false, false);
      union { unsigned int u[4]; short8 v; } pa;
      pa.u[0] = w02[0]; pa.u[1] = w13[0]; pa.u[2] = w02[1]; pa.u[3] = w13[1];

      short8 b0 = *(const short8*)&sVT[ m        * VSTR + kt * 32 + quad * 8];
      short8 b1 = *(const short8*)&sVT[(16 + m)  * VSTR + kt * 32 + quad * 8];
      acc0 = __builtin_amdgcn_mfma_f32_16x16x32_bf16(pa.v, b0, acc0, 0, 0, 0);
      acc1 = __builtin_amdgcn_mfma_f32_16x16x32_bf16(pa.v, b1, acc1, 0, 0, 0);
    }

    // ---- store (C-layout: lane (m,quad) reg r -> out[row = s*16+quad*4+r][h*32 + m (+16)])
    // inverse row-sum for output row quad*4+r lives at lane (quad*4+r): bpermute.
    float* orow = out + ((size_t)b * SEQ + s * 16 + quad * 4) * OC + h * HD + m;
    #pragma unroll
    for (int r = 0; r < 4; ++r) {
      float ilr = __shfl(il, quad * 4 + r);
      orow[r * OC]      = acc0[r] * ilr;
      orow[r * OC + 16] = acc1[r] * ilr;
    }
  }
}

extern "C" void kernel_launch(void* const* d_in, const int* in_sizes, int n_in,
                              void* d_out, int out_size, void* d_ws, size_t ws_size,
                              hipStream_t stream) {
  const float* qkv  = (const float*)d_in[0];
  const float* mask = (const float*)d_in[1];
  float* out = (float*)d_out;
  attn_kernel<<<dim3(2048 * NH), dim3(256), 0, stream>>>(qkv, mask, out);
}